// Round 10
// baseline (1105.297 us; speedup 1.0000x reference)
//
#include <hip/hip_runtime.h>
#include <hip/hip_fp16.h>

#define DIN 128
#define H1  64
#define H2  32
#define NCH 512      // sort chunks
#define BSH 8        // bucket = dst >> BSH (256 nodes/bucket)

typedef _Float16 f16x8 __attribute__((ext_vector_type(8)));
typedef _Float16 f16x4 __attribute__((ext_vector_type(4)));
typedef float    f32x4 __attribute__((ext_vector_type(4)));

// ---- chunk histogram by bucket (LDS only, no global atomics) ----
__global__ __launch_bounds__(256) void k_hist(const int* __restrict__ dst,
        int* __restrict__ H, int E, int NB, int chunk) {
    __shared__ int lh[512];
    int c = blockIdx.x, tid = threadIdx.x;
    for (int b = tid; b < NB; b += 256) lh[b] = 0;
    __syncthreads();
    int e0 = c * chunk, e1 = min(E, e0 + chunk);
    for (int e = e0 + tid; e < e1; e += 256)
        atomicAdd(&lh[dst[e] >> BSH], 1);
    __syncthreads();
    for (int b = tid; b < NB; b += 256) H[(size_t)b * NCH + c] = lh[b];
}

// ---- scan step 1: per-block (1024 elems) exclusive scan + block totals ----
__global__ __launch_bounds__(256) void k_scan1(const int* __restrict__ in,
        int* __restrict__ out, int* __restrict__ partial, int N) {
    int tid = threadIdx.x;
    int base = blockIdx.x * 1024 + tid * 4;
    int v0 = (base + 0 < N) ? in[base + 0] : 0;
    int v1 = (base + 1 < N) ? in[base + 1] : 0;
    int v2 = (base + 2 < N) ? in[base + 2] : 0;
    int v3 = (base + 3 < N) ? in[base + 3] : 0;
    int sum = v0 + v1 + v2 + v3;
    int lane = tid & 63, wid = tid >> 6;
    int x = sum;
#pragma unroll
    for (int off = 1; off < 64; off <<= 1) {
        int y = __shfl_up(x, off, 64);
        if (lane >= off) x += y;
    }
    __shared__ int wsum[4];
    if (lane == 63) wsum[wid] = x;
    __syncthreads();
    int wbase = 0;
    for (int w = 0; w < wid; ++w) wbase += wsum[w];
    int excl = wbase + x - sum;
    if (base + 0 < N) out[base + 0] = excl;
    if (base + 1 < N) out[base + 1] = excl + v0;
    if (base + 2 < N) out[base + 2] = excl + v0 + v1;
    if (base + 3 < N) out[base + 3] = excl + v0 + v1 + v2;
    if (tid == 0) partial[blockIdx.x] = wsum[0] + wsum[1] + wsum[2] + wsum[3];
}

// ---- scan step 2: one-block exclusive scan of block totals (nb <= 256) ----
__global__ __launch_bounds__(256) void k_scan2(int* __restrict__ partial, int nb) {
    int tid = threadIdx.x;
    int v = (tid < nb) ? partial[tid] : 0;
    __shared__ int tmp[256];
    tmp[tid] = v;
    __syncthreads();
    for (int off = 1; off < 256; off <<= 1) {
        int y = (tid >= off) ? tmp[tid - off] : 0;
        __syncthreads();
        tmp[tid] += y;
        __syncthreads();
    }
    if (tid < nb) partial[tid] = tmp[tid] - v;   // exclusive
}

// ---- scan step 3: add block offsets ----
__global__ void k_scan3b(int* __restrict__ a, const int* __restrict__ partial, int n) {
    int i = blockIdx.x * blockDim.x + threadIdx.x;
    if (i < n) a[i] += partial[i >> 10];
}

// ---- bucket sort: chunk c writes its edges into bucket-grouped packed ep ----
//      packed word = src | (dst_local << 20)   (needs N < 2^20, BSH <= 11)
__global__ __launch_bounds__(256) void k_bsort(const int* __restrict__ src,
        const int* __restrict__ dst, const int* __restrict__ H,
        int* __restrict__ ep, int E, int NB, int chunk) {
    __shared__ int cur[512];
    int c = blockIdx.x, tid = threadIdx.x;
    for (int b = tid; b < NB; b += 256) cur[b] = H[(size_t)b * NCH + c];
    __syncthreads();
    int e0 = c * chunk, e1 = min(E, e0 + chunk);
    for (int e = e0 + tid; e < e1; e += 256) {
        int s = src[e], d = dst[e];
        int pos = atomicAdd(&cur[d >> BSH], 1);
        ep[pos] = s | ((d & ((1 << BSH) - 1)) << 20);
    }
}

// ---- per-bucket degree -> dinv (no CSR needed anymore) ----
__global__ __launch_bounds__(256) void k_deg2(const int* __restrict__ ep,
        const int* __restrict__ H, float* __restrict__ dinv, int E, int N, int NB) {
    __shared__ int cnt[256];
    int b = blockIdx.x, tid = threadIdx.x;
    cnt[tid] = 0;
    int bstart = H[(size_t)b * NCH];
    int bend = (b + 1 < NB) ? H[(size_t)(b + 1) * NCH] : E;
    __syncthreads();
    for (int e = bstart + tid; e < bend; e += 256)
        atomicAdd(&cnt[ep[e] >> 20], 1);
    __syncthreads();
    int n = (b << BSH) + tid;
    if (n < N) dinv[n] = rsqrtf((float)cnt[tid] + 1.0f);
}

// ---- MFMA GEMM layer 1: t1h(fp16) = (x @ W1) * dinv ; M=64,N=64,K=128 ----
__global__ __launch_bounds__(256) void k_mgemm1(const float* __restrict__ x,
        const float* __restrict__ W1, const float* __restrict__ dinv,
        _Float16* __restrict__ t1h, int N) {
    __shared__ _Float16 sA[64 * 128];   // 16 KB, row 256 B, XOR-swizzled
    __shared__ _Float16 sB[64 * 128];   // 16 KB, sB[n][k] = W1[k][n], swizzled
    int tid = threadIdx.x;
    int row0 = blockIdx.x * 64;
#pragma unroll
    for (int i = 0; i < 8; ++i) {
        int idx4 = tid + 256 * i;        // 0..2047 float4 slots
        int r = idx4 >> 5, c4 = idx4 & 31;
        int row = row0 + r;
        float4 v = make_float4(0.f, 0.f, 0.f, 0.f);
        if (row < N) v = *(const float4*)&x[(size_t)row * DIN + c4 * 4];
        f16x4 h;
        h[0] = (_Float16)v.x; h[1] = (_Float16)v.y;
        h[2] = (_Float16)v.z; h[3] = (_Float16)v.w;
        int byte = (c4 * 8) ^ ((r & 7) << 4);
        *(f16x4*)((char*)sA + r * 256 + byte) = h;
    }
    {
        int n = tid & 63, kq = tid >> 6;  // kq 0..3, 32 k each
        _Float16 tmp[32];
#pragma unroll
        for (int kk = 0; kk < 32; ++kk)
            tmp[kk] = (_Float16)W1[(size_t)(kq * 32 + kk) * H1 + n];
#pragma unroll
        for (int j = 0; j < 4; ++j) {
            int byte = ((kq * 32 + j * 8) * 2) ^ ((n & 7) << 4);
            *(f16x8*)((char*)sB + n * 256 + byte) = *(f16x8*)&tmp[j * 8];
        }
    }
    __syncthreads();
    int lane = tid & 63, w = tid >> 6;
    int lr = lane & 15, kg = lane >> 4;
    f32x4 acc[4] = {};
    int ar = w * 16 + lr;
    const char* pa = (const char*)sA + ar * 256;
    int axor = (ar & 7) << 4;
#pragma unroll
    for (int ks = 0; ks < 4; ++ks) {
        int kb = ks * 64 + kg * 16;
        f16x8 a = *(const f16x8*)(pa + (kb ^ axor));
#pragma unroll
        for (int nt = 0; nt < 4; ++nt) {
            int bn = nt * 16 + lr;
            f16x8 b = *(const f16x8*)((const char*)sB + bn * 256 + (kb ^ ((bn & 7) << 4)));
            acc[nt] = __builtin_amdgcn_mfma_f32_16x16x32_f16(a, b, acc[nt], 0, 0, 0);
        }
    }
#pragma unroll
    for (int rg = 0; rg < 4; ++rg) {
        int R = row0 + w * 16 + kg * 4 + rg;
        if (R < N) {
            float dv = dinv[R];
#pragma unroll
            for (int nt = 0; nt < 4; ++nt)
                t1h[(size_t)R * H1 + nt * 16 + lr] = (_Float16)(acc[nt][rg] * dv);
        }
    }
}

// ---- MFMA GEMM layer 2: t2h(fp16) = (agg1h @ W2) * dinv ; M=64,N=32,K=64 ----
__global__ __launch_bounds__(256) void k_mgemm2(const _Float16* __restrict__ aggh,
        const float* __restrict__ W2, const float* __restrict__ dinv,
        _Float16* __restrict__ t2h, int N) {
    __shared__ _Float16 sA[64 * 64];    // 8 KB
    __shared__ _Float16 sB[32 * 64];    // 4 KB
    int tid = threadIdx.x;
    int row0 = blockIdx.x * 64;
#pragma unroll
    for (int i = 0; i < 2; ++i) {
        int idx8 = tid + 256 * i;        // 0..511 f16x8 chunks
        int r = idx8 >> 3, c8 = idx8 & 7;
        int row = row0 + r;
        f16x8 h = {};
        if (row < N) h = *(const f16x8*)&aggh[(size_t)row * H1 + c8 * 8];
        int byte = (c8 * 16) ^ ((r & 7) << 4);
        *(f16x8*)((char*)sA + r * 128 + byte) = h;
    }
    {
        int n = tid & 31, kq = tid >> 5;  // kq 0..7, 8 k each
        _Float16 tmp[8];
#pragma unroll
        for (int kk = 0; kk < 8; ++kk)
            tmp[kk] = (_Float16)W2[(size_t)(kq * 8 + kk) * H2 + n];
        int byte = (kq * 16) ^ ((n & 7) << 4);
        *(f16x8*)((char*)sB + n * 128 + byte) = *(f16x8*)&tmp[0];
    }
    __syncthreads();
    int lane = tid & 63, w = tid >> 6;
    int lr = lane & 15, kg = lane >> 4;
    f32x4 acc[2] = {};
    int ar = w * 16 + lr;
    const char* pa = (const char*)sA + ar * 128;
    int axor = (ar & 7) << 4;
#pragma unroll
    for (int ks = 0; ks < 2; ++ks) {
        int kb = ks * 64 + kg * 16;
        f16x8 a = *(const f16x8*)(pa + (kb ^ axor));
#pragma unroll
        for (int nt = 0; nt < 2; ++nt) {
            int bn = nt * 16 + lr;
            f16x8 b = *(const f16x8*)((const char*)sB + bn * 128 + (kb ^ ((bn & 7) << 4)));
            acc[nt] = __builtin_amdgcn_mfma_f32_16x16x32_f16(a, b, acc[nt], 0, 0, 0);
        }
    }
#pragma unroll
    for (int rg = 0; rg < 4; ++rg) {
        int R = row0 + w * 16 + kg * 4 + rg;
        if (R < N) {
            float dv = dinv[R];
#pragma unroll
            for (int nt = 0; nt < 2; ++nt)
                t2h[(size_t)R * H2 + nt * 16 + lr] = (_Float16)(acc[nt][rg] * dv);
        }
    }
}

// ---- push aggregation into LDS: one block per bucket (256 nodes) ----
// acc[256][F] fp32 in LDS; each F-lane group owns one edge (U=8 in flight);
// gather = contiguous row read of t'; ds_add_f32 stride-4B (conflict-free).
// Epilogue: layer1 -> agg1h = fp16(relu(acc*dinv)); layer2 -> out fp32.
template <int LOGF, bool FUSE>
__global__ __launch_bounds__(512) void k_push(const int* __restrict__ ep,
        const int* __restrict__ H, const float* __restrict__ dinv,
        const _Float16* __restrict__ tph, void* __restrict__ outv,
        int E, int N, int NB) {
    constexpr int F = 1 << LOGF;           // feats (64 or 32)
    constexpr int G = 512 >> LOGF;         // edge groups per block (8 or 16)
    constexpr int U = 8;                   // edges in flight per group
    __shared__ float acc[256 << LOGF];     // 64 KB or 32 KB
    int tid = threadIdx.x;
    int b = blockIdx.x;
    int base = b << BSH;
    int bstart = H[(size_t)b * NCH];
    int bend = (b + 1 < NB) ? H[(size_t)(b + 1) * NCH] : E;
    // init acc with self term t'[n] (half2-vectorized, coalesced)
    const __half2* tp2 = (const __half2*)tph;
    constexpr int F2 = F >> 1;
    for (int i2 = tid; i2 < (256 << LOGF) / 2; i2 += 512) {
        int nl = i2 >> (LOGF - 1), fp = i2 & (F2 - 1);
        int n = base + nl;
        float2 f = make_float2(0.f, 0.f);
        if (n < N) f = __half22float2(tp2[(size_t)n * F2 + fp]);
        acc[(nl << LOGF) + fp * 2 + 0] = f.x;
        acc[(nl << LOGF) + fp * 2 + 1] = f.y;
    }
    __syncthreads();
    // main: U independent ep-load -> gather -> ds_add chains per group
    int gid = tid >> LOGF;                 // group id within block
    int j = tid & (F - 1);                 // feature lane
    const __half* th = (const __half*)tph;
    for (int eb = bstart + gid; eb < bend; eb += G * U) {
        int pe[U];
#pragma unroll
        for (int u = 0; u < U; ++u) {
            int e = eb + u * G;
            pe[u] = (e < bend) ? ep[e] : -1;
        }
        float va[U];
#pragma unroll
        for (int u = 0; u < U; ++u)
            va[u] = (pe[u] >= 0)
                ? __half2float(th[((size_t)(pe[u] & 0xFFFFF) << LOGF) + j]) : 0.f;
#pragma unroll
        for (int u = 0; u < U; ++u)
            if (pe[u] >= 0)
                atomicAdd(&acc[((pe[u] >> 20) << LOGF) + j], va[u]);
    }
    __syncthreads();
    // epilogue
    for (int i2 = tid; i2 < (256 << LOGF) / 2; i2 += 512) {
        int nl = i2 >> (LOGF - 1), fp = i2 & (F2 - 1);
        int n = base + nl;
        if (n >= N) continue;
        float dv = dinv[n];
        float vx = acc[(nl << LOGF) + fp * 2 + 0] * dv;
        float vy = acc[(nl << LOGF) + fp * 2 + 1] * dv;
        if (FUSE) {
            ((__half2*)outv)[(size_t)n * F2 + fp] =
                __floats2half2_rn(fmaxf(vx, 0.f), fmaxf(vy, 0.f));
        } else {
            ((float2*)outv)[(size_t)n * F2 + fp] = make_float2(vx, vy);
        }
    }
}

extern "C" void kernel_launch(void* const* d_in, const int* in_sizes, int n_in,
                              void* d_out, int out_size, void* d_ws, size_t ws_size,
                              hipStream_t stream) {
    const float* x  = (const float*)d_in[0];
    const int*   ei = (const int*)d_in[1];
    const float* W1 = (const float*)d_in[2];
    const float* W2 = (const float*)d_in[3];

    const int N = in_sizes[0] / DIN;   // 100000 (< 2^20, required by ep packing)
    const int E = in_sizes[1] / 2;     // 1600000
    const int* src = ei;
    const int* dst = ei + E;

    const int NB    = (N + (1 << BSH) - 1) >> BSH;   // 391 buckets
    const int NBNCH = NB * NCH;                       // 200192
    const int chunk = (E + NCH - 1) / NCH;            // 3125

    // workspace layout (4-byte elems unless noted)
    float*    dinv    = (float*)d_ws;                     // N
    int*      H       = (int*)(dinv + N);                 // NB*NCH
    int*      partial = H + NBNCH;                        // 256
    int*      ep      = partial + 256;                    // E packed ints (6.4 MB)
    _Float16* t1h     = (_Float16*)(ep + E);              // N*64 halves (12.8 MB)
    _Float16* agg1h   = t1h + (size_t)N * H1;             // N*64 halves (12.8 MB)
    _Float16* t2h     = t1h;                              // reuse after push1 done
    float*    out     = (float*)d_out;                    // N*32 fp32

    // --- counting-sort edge grouping (no global atomics, no CSR) ---
    k_hist<<<NCH, 256, 0, stream>>>(dst, H, E, NB, chunk);
    k_scan1<<<(NBNCH + 1023) / 1024, 256, 0, stream>>>(H, H, partial, NBNCH);
    k_scan2<<<1, 256, 0, stream>>>(partial, (NBNCH + 1023) / 1024);
    k_scan3b<<<(NBNCH + 255) / 256, 256, 0, stream>>>(H, partial, NBNCH);
    k_bsort<<<NCH, 256, 0, stream>>>(src, dst, H, ep, E, NB, chunk);
    k_deg2<<<NB, 256, 0, stream>>>(ep, H, dinv, E, N, NB);

    const int ntile = (N + 63) / 64;                 // 1563

    // --- layer 1 ---
    k_mgemm1<<<ntile, 256, 0, stream>>>(x, W1, dinv, t1h, N);
    k_push<6, true><<<NB, 512, 0, stream>>>(ep, H, dinv, t1h, agg1h, E, N, NB);

    // --- layer 2 ---
    k_mgemm2<<<ntile, 256, 0, stream>>>(agg1h, W2, dinv, t2h, N);
    k_push<5, false><<<NB, 512, 0, stream>>>(ep, H, dinv, t2h, out, E, N, NB);
}

// Round 11
// 145.499 us; speedup vs baseline: 7.5966x; 7.5966x over previous
//
#include <hip/hip_runtime.h>
#include <hip/hip_fp16.h>

#define DIN 128
#define H1  64
#define H2  32
#define NCH 512      // sort chunks
#define BSH 8        // bucket = dst >> BSH (256 nodes/bucket)

typedef _Float16 f16x8 __attribute__((ext_vector_type(8)));
typedef _Float16 f16x4 __attribute__((ext_vector_type(4)));
typedef float    f32x4 __attribute__((ext_vector_type(4)));

// ---- chunk histogram by bucket (LDS only, no global atomics) ----
__global__ __launch_bounds__(256) void k_hist(const int* __restrict__ dst,
        int* __restrict__ H, int E, int NB, int chunk) {
    __shared__ int lh[512];
    int c = blockIdx.x, tid = threadIdx.x;
    for (int b = tid; b < NB; b += 256) lh[b] = 0;
    __syncthreads();
    int e0 = c * chunk, e1 = min(E, e0 + chunk);
    for (int e = e0 + tid; e < e1; e += 256)
        atomicAdd(&lh[dst[e] >> BSH], 1);
    __syncthreads();
    for (int b = tid; b < NB; b += 256) H[(size_t)b * NCH + c] = lh[b];
}

// ---- scan step 1: per-block (1024 elems) exclusive scan + block totals ----
__global__ __launch_bounds__(256) void k_scan1(const int* __restrict__ in,
        int* __restrict__ out, int* __restrict__ partial, int N) {
    int tid = threadIdx.x;
    int base = blockIdx.x * 1024 + tid * 4;
    int v0 = (base + 0 < N) ? in[base + 0] : 0;
    int v1 = (base + 1 < N) ? in[base + 1] : 0;
    int v2 = (base + 2 < N) ? in[base + 2] : 0;
    int v3 = (base + 3 < N) ? in[base + 3] : 0;
    int sum = v0 + v1 + v2 + v3;
    int lane = tid & 63, wid = tid >> 6;
    int x = sum;
#pragma unroll
    for (int off = 1; off < 64; off <<= 1) {
        int y = __shfl_up(x, off, 64);
        if (lane >= off) x += y;
    }
    __shared__ int wsum[4];
    if (lane == 63) wsum[wid] = x;
    __syncthreads();
    int wbase = 0;
    for (int w = 0; w < wid; ++w) wbase += wsum[w];
    int excl = wbase + x - sum;
    if (base + 0 < N) out[base + 0] = excl;
    if (base + 1 < N) out[base + 1] = excl + v0;
    if (base + 2 < N) out[base + 2] = excl + v0 + v1;
    if (base + 3 < N) out[base + 3] = excl + v0 + v1 + v2;
    if (tid == 0) partial[blockIdx.x] = wsum[0] + wsum[1] + wsum[2] + wsum[3];
}

// ---- scan step 2: one-block exclusive scan of block totals (nb <= 256) ----
__global__ __launch_bounds__(256) void k_scan2(int* __restrict__ partial, int nb) {
    int tid = threadIdx.x;
    int v = (tid < nb) ? partial[tid] : 0;
    __shared__ int tmp[256];
    tmp[tid] = v;
    __syncthreads();
    for (int off = 1; off < 256; off <<= 1) {
        int y = (tid >= off) ? tmp[tid - off] : 0;
        __syncthreads();
        tmp[tid] += y;
        __syncthreads();
    }
    if (tid < nb) partial[tid] = tmp[tid] - v;   // exclusive
}

// ---- scan step 3: add block offsets ----
__global__ void k_scan3b(int* __restrict__ a, const int* __restrict__ partial, int n) {
    int i = blockIdx.x * blockDim.x + threadIdx.x;
    if (i < n) a[i] += partial[i >> 10];
}

// ---- bucket sort: chunk c writes its edges into bucket-grouped packed ep ----
//      packed word = src | (dst_local << 20)   (needs N < 2^20, BSH <= 11)
__global__ __launch_bounds__(256) void k_bsort(const int* __restrict__ src,
        const int* __restrict__ dst, const int* __restrict__ H,
        int* __restrict__ ep, int E, int NB, int chunk) {
    __shared__ int cur[512];
    int c = blockIdx.x, tid = threadIdx.x;
    for (int b = tid; b < NB; b += 256) cur[b] = H[(size_t)b * NCH + c];
    __syncthreads();
    int e0 = c * chunk, e1 = min(E, e0 + chunk);
    for (int e = e0 + tid; e < e1; e += 256) {
        int s = src[e], d = dst[e];
        int pos = atomicAdd(&cur[d >> BSH], 1);
        ep[pos] = s | ((d & ((1 << BSH) - 1)) << 20);
    }
}

// ---- per-bucket CSR finalize (packed ep) ----
__global__ __launch_bounds__(256) void k_csr(const int* __restrict__ ep,
        const int* __restrict__ H, int* __restrict__ degi, int* __restrict__ rowptr,
        float* __restrict__ dinv, int* __restrict__ csr_src, int E, int N, int NB) {
    __shared__ int cnt[256], pos[256], wsum[4];
    int b = blockIdx.x, tid = threadIdx.x;
    int base = b << BSH;
    cnt[tid] = 0;
    int bstart = H[(size_t)b * NCH];
    int bend = (b + 1 < NB) ? H[(size_t)(b + 1) * NCH] : E;
    __syncthreads();
    for (int e = bstart + tid; e < bend; e += 256)
        atomicAdd(&cnt[ep[e] >> 20], 1);
    __syncthreads();
    int v = cnt[tid];
    int lane = tid & 63, wid = tid >> 6;
    int x = v;
#pragma unroll
    for (int off = 1; off < 64; off <<= 1) {
        int y = __shfl_up(x, off, 64);
        if (lane >= off) x += y;
    }
    if (lane == 63) wsum[wid] = x;
    __syncthreads();
    int wbase = 0;
    for (int w = 0; w < wid; ++w) wbase += wsum[w];
    int excl = wbase + x - v;            // exclusive local prefix
    int n = base + tid;
    if (n < N) {
        degi[n]   = v;
        dinv[n]   = rsqrtf((float)v + 1.0f);
        rowptr[n] = bstart + excl;
    }
    pos[tid] = bstart + excl;
    __syncthreads();
    for (int e = bstart + tid; e < bend; e += 256) {
        int p = ep[e];
        int q = atomicAdd(&pos[p >> 20], 1);
        csr_src[q] = p & 0xFFFFF;
    }
}

// ---- MFMA GEMM layer 1: t1h(fp16) = (x @ W1) * dinv ; M=64,N=64,K=128 ----
__global__ __launch_bounds__(256) void k_mgemm1(const float* __restrict__ x,
        const float* __restrict__ W1, const float* __restrict__ dinv,
        _Float16* __restrict__ t1h, int N) {
    __shared__ _Float16 sA[64 * 128];   // 16 KB, row 256 B, XOR-swizzled
    __shared__ _Float16 sB[64 * 128];   // 16 KB, sB[n][k] = W1[k][n], swizzled
    int tid = threadIdx.x;
    int row0 = blockIdx.x * 64;
#pragma unroll
    for (int i = 0; i < 8; ++i) {
        int idx4 = tid + 256 * i;        // 0..2047 float4 slots
        int r = idx4 >> 5, c4 = idx4 & 31;
        int row = row0 + r;
        float4 v = make_float4(0.f, 0.f, 0.f, 0.f);
        if (row < N) v = *(const float4*)&x[(size_t)row * DIN + c4 * 4];
        f16x4 h;
        h[0] = (_Float16)v.x; h[1] = (_Float16)v.y;
        h[2] = (_Float16)v.z; h[3] = (_Float16)v.w;
        int byte = (c4 * 8) ^ ((r & 7) << 4);
        *(f16x4*)((char*)sA + r * 256 + byte) = h;
    }
    {
        int n = tid & 63, kq = tid >> 6;  // kq 0..3, 32 k each
        _Float16 tmp[32];
#pragma unroll
        for (int kk = 0; kk < 32; ++kk)
            tmp[kk] = (_Float16)W1[(size_t)(kq * 32 + kk) * H1 + n];
#pragma unroll
        for (int j = 0; j < 4; ++j) {
            int byte = ((kq * 32 + j * 8) * 2) ^ ((n & 7) << 4);
            *(f16x8*)((char*)sB + n * 256 + byte) = *(f16x8*)&tmp[j * 8];
        }
    }
    __syncthreads();
    int lane = tid & 63, w = tid >> 6;
    int lr = lane & 15, kg = lane >> 4;
    f32x4 acc[4] = {};
    int ar = w * 16 + lr;
    const char* pa = (const char*)sA + ar * 256;
    int axor = (ar & 7) << 4;
#pragma unroll
    for (int ks = 0; ks < 4; ++ks) {
        int kb = ks * 64 + kg * 16;
        f16x8 a = *(const f16x8*)(pa + (kb ^ axor));
#pragma unroll
        for (int nt = 0; nt < 4; ++nt) {
            int bn = nt * 16 + lr;
            f16x8 b = *(const f16x8*)((const char*)sB + bn * 256 + (kb ^ ((bn & 7) << 4)));
            acc[nt] = __builtin_amdgcn_mfma_f32_16x16x32_f16(a, b, acc[nt], 0, 0, 0);
        }
    }
#pragma unroll
    for (int rg = 0; rg < 4; ++rg) {
        int R = row0 + w * 16 + kg * 4 + rg;
        if (R < N) {
            float dv = dinv[R];
#pragma unroll
            for (int nt = 0; nt < 4; ++nt)
                t1h[(size_t)R * H1 + nt * 16 + lr] = (_Float16)(acc[nt][rg] * dv);
        }
    }
}

// ---- MFMA GEMM layer 2: t2h(fp16) = (agg1h @ W2) * dinv ; M=64,N=32,K=64 ----
__global__ __launch_bounds__(256) void k_mgemm2(const _Float16* __restrict__ aggh,
        const float* __restrict__ W2, const float* __restrict__ dinv,
        _Float16* __restrict__ t2h, int N) {
    __shared__ _Float16 sA[64 * 64];    // 8 KB
    __shared__ _Float16 sB[32 * 64];    // 4 KB
    int tid = threadIdx.x;
    int row0 = blockIdx.x * 64;
#pragma unroll
    for (int i = 0; i < 2; ++i) {
        int idx8 = tid + 256 * i;        // 0..511 f16x8 chunks
        int r = idx8 >> 3, c8 = idx8 & 7;
        int row = row0 + r;
        f16x8 h = {};
        if (row < N) h = *(const f16x8*)&aggh[(size_t)row * H1 + c8 * 8];
        int byte = (c8 * 16) ^ ((r & 7) << 4);
        *(f16x8*)((char*)sA + r * 128 + byte) = h;
    }
    {
        int n = tid & 31, kq = tid >> 5;  // kq 0..7, 8 k each
        _Float16 tmp[8];
#pragma unroll
        for (int kk = 0; kk < 8; ++kk)
            tmp[kk] = (_Float16)W2[(size_t)(kq * 8 + kk) * H2 + n];
        int byte = (kq * 16) ^ ((n & 7) << 4);
        *(f16x8*)((char*)sB + n * 128 + byte) = *(f16x8*)&tmp[0];
    }
    __syncthreads();
    int lane = tid & 63, w = tid >> 6;
    int lr = lane & 15, kg = lane >> 4;
    f32x4 acc[2] = {};
    int ar = w * 16 + lr;
    const char* pa = (const char*)sA + ar * 128;
    int axor = (ar & 7) << 4;
#pragma unroll
    for (int ks = 0; ks < 2; ++ks) {
        int kb = ks * 64 + kg * 16;
        f16x8 a = *(const f16x8*)(pa + (kb ^ axor));
#pragma unroll
        for (int nt = 0; nt < 2; ++nt) {
            int bn = nt * 16 + lr;
            f16x8 b = *(const f16x8*)((const char*)sB + bn * 128 + (kb ^ ((bn & 7) << 4)));
            acc[nt] = __builtin_amdgcn_mfma_f32_16x16x32_f16(a, b, acc[nt], 0, 0, 0);
        }
    }
#pragma unroll
    for (int rg = 0; rg < 4; ++rg) {
        int R = row0 + w * 16 + kg * 4 + rg;
        if (R < N) {
            float dv = dinv[R];
#pragma unroll
            for (int nt = 0; nt < 2; ++nt)
                t2h[(size_t)R * H2 + nt * 16 + lr] = (_Float16)(acc[nt][rg] * dv);
        }
    }
}

// ---- pull aggregation, masked 8-wide batches (fp16 table, fp32 accum) ----
// All loads/gathers unconditional (csr_src padded by 8; invalid lanes clamp
// index to 0 and cndmask the contribution) -> no serial tail, 8 gathers in
// flight per node, 16 per wave.
template <int LOGF2, bool FUSE>
__global__ __launch_bounds__(256) void k_aggv(const int* __restrict__ rowptr,
        const int* __restrict__ degi, const int* __restrict__ csr_src,
        const float* __restrict__ dinv, const __half2* __restrict__ tp,
        void* __restrict__ outv, int N) {
    const int F2 = 1 << LOGF2;
    int local = threadIdx.x >> LOGF2;
    int j = threadIdx.x & (F2 - 1);
    int n = blockIdx.x * (256 >> LOGF2) + local;
    if (n >= N) return;
    int start = rowptr[n];
    int deg = degi[n];
    float2 f = __half22float2(tp[((size_t)n << LOGF2) + j]);   // self term
    float ax = f.x, ay = f.y;
    for (int k = 0; k < deg; k += 8) {
        int raw[8];
#pragma unroll
        for (int u = 0; u < 8; ++u)
            raw[u] = csr_src[start + k + u];          // padded: always in-bounds
#pragma unroll
        for (int u = 0; u < 8; ++u) {
            bool valid = (k + u) < deg;
            int s = valid ? raw[u] : 0;               // clamp -> row 0 (L1-hot)
            float2 g = __half22float2(tp[((size_t)s << LOGF2) + j]);
            ax += valid ? g.x : 0.f;
            ay += valid ? g.y : 0.f;
        }
    }
    float dv = dinv[n];
    size_t idx = ((size_t)n << LOGF2) + j;
    if (FUSE) {
        ((__half2*)outv)[idx] =
            __floats2half2_rn(fmaxf(ax * dv, 0.f), fmaxf(ay * dv, 0.f));
    } else {
        ((float2*)outv)[idx] = make_float2(ax * dv, ay * dv);
    }
}

extern "C" void kernel_launch(void* const* d_in, const int* in_sizes, int n_in,
                              void* d_out, int out_size, void* d_ws, size_t ws_size,
                              hipStream_t stream) {
    const float* x  = (const float*)d_in[0];
    const int*   ei = (const int*)d_in[1];
    const float* W1 = (const float*)d_in[2];
    const float* W2 = (const float*)d_in[3];

    const int N = in_sizes[0] / DIN;   // 100000 (< 2^20, required by ep packing)
    const int E = in_sizes[1] / 2;     // 1600000
    const int* src = ei;
    const int* dst = ei + E;

    const int NB    = (N + (1 << BSH) - 1) >> BSH;   // 391 buckets
    const int NBNCH = NB * NCH;                       // 200192
    const int chunk = (E + NCH - 1) / NCH;            // 3125

    // workspace layout (4-byte elems unless noted)
    float*    dinv    = (float*)d_ws;                     // N
    int*      degi    = (int*)(dinv + N);                 // N
    int*      rowptr  = degi + N;                         // N
    int*      H       = rowptr + N;                       // NB*NCH
    int*      partial = H + NBNCH;                        // 256
    int*      csr_src = partial + 256;                    // E + 8 (pad for k_aggv)
    _Float16* t1h     = (_Float16*)(csr_src + E + 8);     // N*64 halves (12.8 MB)
    _Float16* agg1h   = t1h + (size_t)N * H1;             // N*64 halves (12.8 MB)
    _Float16* t2h     = t1h;                              // reuse after agg1h built
    float*    out     = (float*)d_out;                    // N*32 fp32
    int*      ep      = (int*)t1h;                        // E packed ints (6.4 MB),
                                                          // consumed by k_csr before
                                                          // gemm1 writes t1h

    // --- counting-sort CSR build (no global atomics) ---
    k_hist<<<NCH, 256, 0, stream>>>(dst, H, E, NB, chunk);
    k_scan1<<<(NBNCH + 1023) / 1024, 256, 0, stream>>>(H, H, partial, NBNCH);
    k_scan2<<<1, 256, 0, stream>>>(partial, (NBNCH + 1023) / 1024);
    k_scan3b<<<(NBNCH + 255) / 256, 256, 0, stream>>>(H, partial, NBNCH);
    k_bsort<<<NCH, 256, 0, stream>>>(src, dst, H, ep, E, NB, chunk);
    k_csr<<<NB, 256, 0, stream>>>(ep, H, degi, rowptr, dinv, csr_src, E, N, NB);

    const int ntile = (N + 63) / 64;                 // 1563

    // --- layer 1 ---
    k_mgemm1<<<ntile, 256, 0, stream>>>(x, W1, dinv, t1h, N);
    k_aggv<5, true><<<(N + 7) / 8, 256, 0, stream>>>(rowptr, degi, csr_src, dinv,
                                                     (const __half2*)t1h, agg1h, N);

    // --- layer 2 ---
    k_mgemm2<<<ntile, 256, 0, stream>>>(agg1h, W2, dinv, t2h, N);
    k_aggv<4, false><<<(N + 15) / 16, 256, 0, stream>>>(rowptr, degi, csr_src, dinv,
                                                        (const __half2*)t2h, out, N);
}

// Round 12
// 138.709 us; speedup vs baseline: 7.9685x; 1.0490x over previous
//
#include <hip/hip_runtime.h>
#include <hip/hip_fp16.h>

#define DIN 128
#define H1  64
#define H2  32
#define NCH 512      // sort chunks
#define BSH 8        // bucket = dst >> BSH (256 nodes/bucket)

typedef _Float16 f16x8 __attribute__((ext_vector_type(8)));
typedef _Float16 f16x4 __attribute__((ext_vector_type(4)));
typedef float    f32x4 __attribute__((ext_vector_type(4)));

// ---- chunk histogram by bucket (LDS only, no global atomics) ----
__global__ __launch_bounds__(256) void k_hist(const int* __restrict__ dst,
        int* __restrict__ H, int E, int NB, int chunk) {
    __shared__ int lh[512];
    int c = blockIdx.x, tid = threadIdx.x;
    for (int b = tid; b < NB; b += 256) lh[b] = 0;
    __syncthreads();
    int e0 = c * chunk, e1 = min(E, e0 + chunk);
    for (int e = e0 + tid; e < e1; e += 256)
        atomicAdd(&lh[dst[e] >> BSH], 1);
    __syncthreads();
    for (int b = tid; b < NB; b += 256) H[(size_t)b * NCH + c] = lh[b];
}

// ---- scan step 1: per-block (1024 elems) exclusive scan + block totals ----
__global__ __launch_bounds__(256) void k_scan1(const int* __restrict__ in,
        int* __restrict__ out, int* __restrict__ partial, int N) {
    int tid = threadIdx.x;
    int base = blockIdx.x * 1024 + tid * 4;
    int v0 = (base + 0 < N) ? in[base + 0] : 0;
    int v1 = (base + 1 < N) ? in[base + 1] : 0;
    int v2 = (base + 2 < N) ? in[base + 2] : 0;
    int v3 = (base + 3 < N) ? in[base + 3] : 0;
    int sum = v0 + v1 + v2 + v3;
    int lane = tid & 63, wid = tid >> 6;
    int x = sum;
#pragma unroll
    for (int off = 1; off < 64; off <<= 1) {
        int y = __shfl_up(x, off, 64);
        if (lane >= off) x += y;
    }
    __shared__ int wsum[4];
    if (lane == 63) wsum[wid] = x;
    __syncthreads();
    int wbase = 0;
    for (int w = 0; w < wid; ++w) wbase += wsum[w];
    int excl = wbase + x - sum;
    if (base + 0 < N) out[base + 0] = excl;
    if (base + 1 < N) out[base + 1] = excl + v0;
    if (base + 2 < N) out[base + 2] = excl + v0 + v1;
    if (base + 3 < N) out[base + 3] = excl + v0 + v1 + v2;
    if (tid == 0) partial[blockIdx.x] = wsum[0] + wsum[1] + wsum[2] + wsum[3];
}

// ---- scan step 2: one-block exclusive scan of block totals (nb <= 256) ----
__global__ __launch_bounds__(256) void k_scan2(int* __restrict__ partial, int nb) {
    int tid = threadIdx.x;
    int v = (tid < nb) ? partial[tid] : 0;
    __shared__ int tmp[256];
    tmp[tid] = v;
    __syncthreads();
    for (int off = 1; off < 256; off <<= 1) {
        int y = (tid >= off) ? tmp[tid - off] : 0;
        __syncthreads();
        tmp[tid] += y;
        __syncthreads();
    }
    if (tid < nb) partial[tid] = tmp[tid] - v;   // exclusive
}

// ---- scan step 3: add block offsets ----
__global__ void k_scan3b(int* __restrict__ a, const int* __restrict__ partial, int n) {
    int i = blockIdx.x * blockDim.x + threadIdx.x;
    if (i < n) a[i] += partial[i >> 10];
}

// ---- bucket sort: chunk c writes its edges into bucket-grouped packed ep ----
//      packed word = src | (dst_local << 20)   (needs N < 2^20, BSH <= 11)
__global__ __launch_bounds__(256) void k_bsort(const int* __restrict__ src,
        const int* __restrict__ dst, const int* __restrict__ H,
        int* __restrict__ ep, int E, int NB, int chunk) {
    __shared__ int cur[512];
    int c = blockIdx.x, tid = threadIdx.x;
    for (int b = tid; b < NB; b += 256) cur[b] = H[(size_t)b * NCH + c];
    __syncthreads();
    int e0 = c * chunk, e1 = min(E, e0 + chunk);
    for (int e = e0 + tid; e < e1; e += 256) {
        int s = src[e], d = dst[e];
        int pos = atomicAdd(&cur[d >> BSH], 1);
        ep[pos] = s | ((d & ((1 << BSH) - 1)) << 20);
    }
}

// ---- per-bucket CSR finalize (packed ep) ----
__global__ __launch_bounds__(256) void k_csr(const int* __restrict__ ep,
        const int* __restrict__ H, int* __restrict__ degi, int* __restrict__ rowptr,
        float* __restrict__ dinv, int* __restrict__ csr_src, int E, int N, int NB) {
    __shared__ int cnt[256], pos[256], wsum[4];
    int b = blockIdx.x, tid = threadIdx.x;
    int base = b << BSH;
    cnt[tid] = 0;
    int bstart = H[(size_t)b * NCH];
    int bend = (b + 1 < NB) ? H[(size_t)(b + 1) * NCH] : E;
    __syncthreads();
    for (int e = bstart + tid; e < bend; e += 256)
        atomicAdd(&cnt[ep[e] >> 20], 1);
    __syncthreads();
    int v = cnt[tid];
    int lane = tid & 63, wid = tid >> 6;
    int x = v;
#pragma unroll
    for (int off = 1; off < 64; off <<= 1) {
        int y = __shfl_up(x, off, 64);
        if (lane >= off) x += y;
    }
    if (lane == 63) wsum[wid] = x;
    __syncthreads();
    int wbase = 0;
    for (int w = 0; w < wid; ++w) wbase += wsum[w];
    int excl = wbase + x - v;            // exclusive local prefix
    int n = base + tid;
    if (n < N) {
        degi[n]   = v;
        dinv[n]   = rsqrtf((float)v + 1.0f);
        rowptr[n] = bstart + excl;
    }
    pos[tid] = bstart + excl;
    __syncthreads();
    for (int e = bstart + tid; e < bend; e += 256) {
        int p = ep[e];
        int q = atomicAdd(&pos[p >> 20], 1);
        csr_src[q] = p & 0xFFFFF;
    }
}

// ---- MFMA GEMM layer 1: t1 sub-tables (fp16) = (x @ W1) * dinv ----
// Output feature-split: sub-table nt holds feats [nt*16, nt*16+16), N x 16 halves.
__global__ __launch_bounds__(256) void k_mgemm1(const float* __restrict__ x,
        const float* __restrict__ W1, const float* __restrict__ dinv,
        _Float16* __restrict__ t1h, int N) {
    __shared__ _Float16 sA[64 * 128];   // 16 KB, row 256 B, XOR-swizzled
    __shared__ _Float16 sB[64 * 128];   // 16 KB, sB[n][k] = W1[k][n], swizzled
    int tid = threadIdx.x;
    int row0 = blockIdx.x * 64;
#pragma unroll
    for (int i = 0; i < 8; ++i) {
        int idx4 = tid + 256 * i;        // 0..2047 float4 slots
        int r = idx4 >> 5, c4 = idx4 & 31;
        int row = row0 + r;
        float4 v = make_float4(0.f, 0.f, 0.f, 0.f);
        if (row < N) v = *(const float4*)&x[(size_t)row * DIN + c4 * 4];
        f16x4 h;
        h[0] = (_Float16)v.x; h[1] = (_Float16)v.y;
        h[2] = (_Float16)v.z; h[3] = (_Float16)v.w;
        int byte = (c4 * 8) ^ ((r & 7) << 4);
        *(f16x4*)((char*)sA + r * 256 + byte) = h;
    }
    {
        int n = tid & 63, kq = tid >> 6;  // kq 0..3, 32 k each
        _Float16 tmp[32];
#pragma unroll
        for (int kk = 0; kk < 32; ++kk)
            tmp[kk] = (_Float16)W1[(size_t)(kq * 32 + kk) * H1 + n];
#pragma unroll
        for (int j = 0; j < 4; ++j) {
            int byte = ((kq * 32 + j * 8) * 2) ^ ((n & 7) << 4);
            *(f16x8*)((char*)sB + n * 256 + byte) = *(f16x8*)&tmp[j * 8];
        }
    }
    __syncthreads();
    int lane = tid & 63, w = tid >> 6;
    int lr = lane & 15, kg = lane >> 4;
    f32x4 acc[4] = {};
    int ar = w * 16 + lr;
    const char* pa = (const char*)sA + ar * 256;
    int axor = (ar & 7) << 4;
#pragma unroll
    for (int ks = 0; ks < 4; ++ks) {
        int kb = ks * 64 + kg * 16;
        f16x8 a = *(const f16x8*)(pa + (kb ^ axor));
#pragma unroll
        for (int nt = 0; nt < 4; ++nt) {
            int bn = nt * 16 + lr;
            f16x8 b = *(const f16x8*)((const char*)sB + bn * 256 + (kb ^ ((bn & 7) << 4)));
            acc[nt] = __builtin_amdgcn_mfma_f32_16x16x32_f16(a, b, acc[nt], 0, 0, 0);
        }
    }
#pragma unroll
    for (int rg = 0; rg < 4; ++rg) {
        int R = row0 + w * 16 + kg * 4 + rg;
        if (R < N) {
            float dv = dinv[R];
#pragma unroll
            for (int nt = 0; nt < 4; ++nt)
                t1h[(size_t)nt * N * 16 + (size_t)R * 16 + lr] =
                    (_Float16)(acc[nt][rg] * dv);
        }
    }
}

// ---- MFMA GEMM layer 2: t2 sub-tables (fp16) = (agg1 @ W2) * dinv ----
// A input read from the 4 feature-split agg1 sub-tables; output 2 sub-tables.
__global__ __launch_bounds__(256) void k_mgemm2(const _Float16* __restrict__ aggh,
        const float* __restrict__ W2, const float* __restrict__ dinv,
        _Float16* __restrict__ t2h, int N) {
    __shared__ _Float16 sA[64 * 64];    // 8 KB
    __shared__ _Float16 sB[32 * 64];    // 4 KB
    int tid = threadIdx.x;
    int row0 = blockIdx.x * 64;
#pragma unroll
    for (int i = 0; i < 2; ++i) {
        int idx8 = tid + 256 * i;        // 0..511 f16x8 chunks
        int r = idx8 >> 3, c8 = idx8 & 7;
        int row = row0 + r;
        f16x8 h = {};
        if (row < N) {
            int q = c8 >> 1, h8 = c8 & 1;   // sub-table, half within sub-table
            h = *(const f16x8*)&aggh[(size_t)q * N * 16 + (size_t)row * 16 + h8 * 8];
        }
        int byte = (c8 * 16) ^ ((r & 7) << 4);
        *(f16x8*)((char*)sA + r * 128 + byte) = h;
    }
    {
        int n = tid & 31, kq = tid >> 5;  // kq 0..7, 8 k each
        _Float16 tmp[8];
#pragma unroll
        for (int kk = 0; kk < 8; ++kk)
            tmp[kk] = (_Float16)W2[(size_t)(kq * 8 + kk) * H2 + n];
        int byte = (kq * 16) ^ ((n & 7) << 4);
        *(f16x8*)((char*)sB + n * 128 + byte) = *(f16x8*)&tmp[0];
    }
    __syncthreads();
    int lane = tid & 63, w = tid >> 6;
    int lr = lane & 15, kg = lane >> 4;
    f32x4 acc[2] = {};
    int ar = w * 16 + lr;
    const char* pa = (const char*)sA + ar * 128;
    int axor = (ar & 7) << 4;
#pragma unroll
    for (int ks = 0; ks < 2; ++ks) {
        int kb = ks * 64 + kg * 16;
        f16x8 a = *(const f16x8*)(pa + (kb ^ axor));
#pragma unroll
        for (int nt = 0; nt < 2; ++nt) {
            int bn = nt * 16 + lr;
            f16x8 b = *(const f16x8*)((const char*)sB + bn * 128 + (kb ^ ((bn & 7) << 4)));
            acc[nt] = __builtin_amdgcn_mfma_f32_16x16x32_f16(a, b, acc[nt], 0, 0, 0);
        }
    }
#pragma unroll
    for (int rg = 0; rg < 4; ++rg) {
        int R = row0 + w * 16 + kg * 4 + rg;
        if (R < N) {
            float dv = dinv[R];
#pragma unroll
            for (int nt = 0; nt < 2; ++nt)
                t2h[(size_t)nt * N * 16 + (size_t)R * 16 + lr] =
                    (_Float16)(acc[nt][rg] * dv);
        }
    }
}

// ---- feature-split pull aggregation pass (16 feats/pass, L2-resident slice) ----
// blockIdx.y = pass q; sub-table q is N x 16 halves (3.2 MB -> fits per-XCD L2).
// 8 lanes per node (half2 each), masked 8-wide edge batches (csr padded by 8).
// FUSE: agg1 sub-table q = fp16(relu(acc*dinv)); else out[n][32] fp32 slice q.
template <bool FUSE>
__global__ __launch_bounds__(256) void k_aggp(const int* __restrict__ rowptr,
        const int* __restrict__ degi, const int* __restrict__ csr_src,
        const float* __restrict__ dinv, const __half2* __restrict__ tph,
        void* __restrict__ outv, int N) {
    int q = blockIdx.y;
    const __half2* tp = tph + (size_t)q * N * 8;   // this pass's sub-table
    int local = threadIdx.x >> 3;                  // node within block (0..31)
    int j = threadIdx.x & 7;                       // half2 lane within node
    int n = blockIdx.x * 32 + local;
    if (n >= N) return;
    int start = rowptr[n];
    int deg = degi[n];
    float2 f = __half22float2(tp[(size_t)n * 8 + j]);   // self term
    float ax = f.x, ay = f.y;
    for (int k = 0; k < deg; k += 8) {
        int raw[8];
#pragma unroll
        for (int u = 0; u < 8; ++u)
            raw[u] = csr_src[start + k + u];       // padded: always in-bounds
#pragma unroll
        for (int u = 0; u < 8; ++u) {
            bool valid = (k + u) < deg;
            int s = valid ? raw[u] : 0;            // clamp -> row 0 (L2-hot)
            float2 g = __half22float2(tp[(size_t)s * 8 + j]);
            ax += valid ? g.x : 0.f;
            ay += valid ? g.y : 0.f;
        }
    }
    float dv = dinv[n];
    if (FUSE) {
        ((__half2*)outv)[(size_t)q * N * 8 + (size_t)n * 8 + j] =
            __floats2half2_rn(fmaxf(ax * dv, 0.f), fmaxf(ay * dv, 0.f));
    } else {
        ((float2*)outv)[(size_t)n * 16 + (size_t)q * 8 + j] =
            make_float2(ax * dv, ay * dv);
    }
}

extern "C" void kernel_launch(void* const* d_in, const int* in_sizes, int n_in,
                              void* d_out, int out_size, void* d_ws, size_t ws_size,
                              hipStream_t stream) {
    const float* x  = (const float*)d_in[0];
    const int*   ei = (const int*)d_in[1];
    const float* W1 = (const float*)d_in[2];
    const float* W2 = (const float*)d_in[3];

    const int N = in_sizes[0] / DIN;   // 100000 (< 2^20, required by ep packing)
    const int E = in_sizes[1] / 2;     // 1600000
    const int* src = ei;
    const int* dst = ei + E;

    const int NB    = (N + (1 << BSH) - 1) >> BSH;   // 391 buckets
    const int NBNCH = NB * NCH;                       // 200192
    const int chunk = (E + NCH - 1) / NCH;            // 3125

    // workspace layout (4-byte elems unless noted)
    float*    dinv    = (float*)d_ws;                     // N
    int*      degi    = (int*)(dinv + N);                 // N
    int*      rowptr  = degi + N;                         // N
    int*      H       = rowptr + N;                       // NB*NCH
    int*      partial = H + NBNCH;                        // 256
    int*      csr_src = partial + 256;                    // E + 8 (pad for k_aggp)
    _Float16* t1h     = (_Float16*)(csr_src + E + 8);     // 4 sub-tables N*16 (12.8 MB)
    _Float16* agg1h   = t1h + (size_t)N * H1;             // 4 sub-tables N*16 (12.8 MB)
    _Float16* t2h     = t1h;                              // 2 sub-tables, reuse
    float*    out     = (float*)d_out;                    // N*32 fp32
    int*      ep      = (int*)t1h;                        // E packed ints (6.4 MB),
                                                          // consumed by k_csr before
                                                          // gemm1 writes t1h

    // --- counting-sort CSR build (no global atomics) ---
    k_hist<<<NCH, 256, 0, stream>>>(dst, H, E, NB, chunk);
    k_scan1<<<(NBNCH + 1023) / 1024, 256, 0, stream>>>(H, H, partial, NBNCH);
    k_scan2<<<1, 256, 0, stream>>>(partial, (NBNCH + 1023) / 1024);
    k_scan3b<<<(NBNCH + 255) / 256, 256, 0, stream>>>(H, partial, NBNCH);
    k_bsort<<<NCH, 256, 0, stream>>>(src, dst, H, ep, E, NB, chunk);
    k_csr<<<NB, 256, 0, stream>>>(ep, H, degi, rowptr, dinv, csr_src, E, N, NB);

    const int ntile = (N + 63) / 64;                 // 1563
    const int nagg  = (N + 31) / 32;                 // 3125

    // --- layer 1 ---
    k_mgemm1<<<ntile, 256, 0, stream>>>(x, W1, dinv, t1h, N);
    {
        dim3 g(nagg, 4);   // 4 feature passes of 16 feats each
        k_aggp<true><<<g, 256, 0, stream>>>(rowptr, degi, csr_src, dinv,
                                            (const __half2*)t1h, agg1h, N);
    }

    // --- layer 2 ---
    k_mgemm2<<<ntile, 256, 0, stream>>>(agg1h, W2, dinv, t2h, N);
    {
        dim3 g(nagg, 2);   // 2 feature passes of 16 feats each
        k_aggp<false><<<g, 256, 0, stream>>>(rowptr, degi, csr_src, dinv,
                                             (const __half2*)t2h, out, N);
    }
}

// Round 13
// 128.281 us; speedup vs baseline: 8.6162x; 1.0813x over previous
//
#include <hip/hip_runtime.h>
#include <hip/hip_fp16.h>

#define DIN 128
#define H1  64
#define H2  32
#define NCH 512      // sort chunks
#define BSH 8        // bucket = dst >> BSH (256 nodes/bucket)

typedef _Float16 f16x8 __attribute__((ext_vector_type(8)));
typedef _Float16 f16x4 __attribute__((ext_vector_type(4)));
typedef float    f32x4 __attribute__((ext_vector_type(4)));

// ---- chunk histogram by bucket (LDS only, no global atomics) ----
__global__ __launch_bounds__(256) void k_hist(const int* __restrict__ dst,
        int* __restrict__ H, int E, int NB, int chunk) {
    __shared__ int lh[512];
    int c = blockIdx.x, tid = threadIdx.x;
    for (int b = tid; b < NB; b += 256) lh[b] = 0;
    __syncthreads();
    int e0 = c * chunk, e1 = min(E, e0 + chunk);
    for (int e = e0 + tid; e < e1; e += 256)
        atomicAdd(&lh[dst[e] >> BSH], 1);
    __syncthreads();
    for (int b = tid; b < NB; b += 256) H[(size_t)b * NCH + c] = lh[b];
}

// ---- scan step 1: per-block (1024 elems) exclusive scan + block totals ----
__global__ __launch_bounds__(256) void k_scan1(const int* __restrict__ in,
        int* __restrict__ out, int* __restrict__ partial, int N) {
    int tid = threadIdx.x;
    int base = blockIdx.x * 1024 + tid * 4;
    int v0 = (base + 0 < N) ? in[base + 0] : 0;
    int v1 = (base + 1 < N) ? in[base + 1] : 0;
    int v2 = (base + 2 < N) ? in[base + 2] : 0;
    int v3 = (base + 3 < N) ? in[base + 3] : 0;
    int sum = v0 + v1 + v2 + v3;
    int lane = tid & 63, wid = tid >> 6;
    int x = sum;
#pragma unroll
    for (int off = 1; off < 64; off <<= 1) {
        int y = __shfl_up(x, off, 64);
        if (lane >= off) x += y;
    }
    __shared__ int wsum[4];
    if (lane == 63) wsum[wid] = x;
    __syncthreads();
    int wbase = 0;
    for (int w = 0; w < wid; ++w) wbase += wsum[w];
    int excl = wbase + x - sum;
    if (base + 0 < N) out[base + 0] = excl;
    if (base + 1 < N) out[base + 1] = excl + v0;
    if (base + 2 < N) out[base + 2] = excl + v0 + v1;
    if (base + 3 < N) out[base + 3] = excl + v0 + v1 + v2;
    if (tid == 0) partial[blockIdx.x] = wsum[0] + wsum[1] + wsum[2] + wsum[3];
}

// ---- scan step 2: one-block exclusive scan of block totals (nb <= 256) ----
__global__ __launch_bounds__(256) void k_scan2(int* __restrict__ partial, int nb) {
    int tid = threadIdx.x;
    int v = (tid < nb) ? partial[tid] : 0;
    __shared__ int tmp[256];
    tmp[tid] = v;
    __syncthreads();
    for (int off = 1; off < 256; off <<= 1) {
        int y = (tid >= off) ? tmp[tid - off] : 0;
        __syncthreads();
        tmp[tid] += y;
        __syncthreads();
    }
    if (tid < nb) partial[tid] = tmp[tid] - v;   // exclusive
}

// ---- scan step 3: add block offsets ----
__global__ void k_scan3b(int* __restrict__ a, const int* __restrict__ partial, int n) {
    int i = blockIdx.x * blockDim.x + threadIdx.x;
    if (i < n) a[i] += partial[i >> 10];
}

// ---- bucket sort: chunk c writes its edges into bucket-grouped packed ep ----
//      packed word = src | (dst_local << 20)   (needs N < 2^20, BSH <= 11)
__global__ __launch_bounds__(256) void k_bsort(const int* __restrict__ src,
        const int* __restrict__ dst, const int* __restrict__ H,
        int* __restrict__ ep, int E, int NB, int chunk) {
    __shared__ int cur[512];
    int c = blockIdx.x, tid = threadIdx.x;
    for (int b = tid; b < NB; b += 256) cur[b] = H[(size_t)b * NCH + c];
    __syncthreads();
    int e0 = c * chunk, e1 = min(E, e0 + chunk);
    for (int e = e0 + tid; e < e1; e += 256) {
        int s = src[e], d = dst[e];
        int pos = atomicAdd(&cur[d >> BSH], 1);
        ep[pos] = s | ((d & ((1 << BSH) - 1)) << 20);
    }
}

// ---- CSR finalize A: per-bucket degree count + 8-aligned local scan ----
__global__ __launch_bounds__(256) void k_csrA(const int* __restrict__ ep,
        const int* __restrict__ H, int* __restrict__ degi, float* __restrict__ dinv,
        int* __restrict__ lexcl, int* __restrict__ btot, int E, int N, int NB) {
    __shared__ int cnt[256], wsum[4];
    int b = blockIdx.x, tid = threadIdx.x;
    cnt[tid] = 0;
    int bstart = H[(size_t)b * NCH];
    int bend = (b + 1 < NB) ? H[(size_t)(b + 1) * NCH] : E;
    __syncthreads();
    for (int e = bstart + tid; e < bend; e += 256)
        atomicAdd(&cnt[ep[e] >> 20], 1);
    __syncthreads();
    int v = cnt[tid];
    int n = (b << BSH) + tid;
    int d8 = (n < N) ? ((v + 7) & ~7) : 0;       // 8-aligned slot size
    int lane = tid & 63, wid = tid >> 6;
    int x = d8;
#pragma unroll
    for (int off = 1; off < 64; off <<= 1) {
        int y = __shfl_up(x, off, 64);
        if (lane >= off) x += y;
    }
    if (lane == 63) wsum[wid] = x;
    __syncthreads();
    int wbase = 0;
    for (int w = 0; w < wid; ++w) wbase += wsum[w];
    int excl = wbase + x - d8;                   // exclusive aligned prefix
    if (n < N) {
        degi[n]  = v;
        dinv[n]  = rsqrtf((float)v + 1.0f);
        lexcl[n] = excl;
    }
    if (tid == 0) btot[b] = wsum[0] + wsum[1] + wsum[2] + wsum[3];
}

// ---- bucket-total exclusive scan (nb <= 512), one block ----
__global__ __launch_bounds__(256) void k_scanC(int* __restrict__ a, int nb) {
    int tid = threadIdx.x;
    int i0 = 2 * tid, i1 = 2 * tid + 1;
    int v0 = (i0 < nb) ? a[i0] : 0;
    int v1 = (i1 < nb) ? a[i1] : 0;
    int p = v0 + v1;
    __shared__ int tmp[256];
    tmp[tid] = p;
    __syncthreads();
    for (int off = 1; off < 256; off <<= 1) {
        int y = (tid >= off) ? tmp[tid - off] : 0;
        __syncthreads();
        tmp[tid] += y;
        __syncthreads();
    }
    int excl = tmp[tid] - p;
    if (i0 < nb) a[i0] = excl;
    if (i1 < nb) a[i1] = excl + v0;
}

// ---- CSR finalize B: final aligned rowptr, scatter, pad-fill with N ----
__global__ __launch_bounds__(256) void k_csrB(const int* __restrict__ ep,
        const int* __restrict__ H, const int* __restrict__ degi,
        const int* __restrict__ bbase, const int* __restrict__ lexcl,
        int* __restrict__ rowptr, int* __restrict__ csr_src, int E, int N, int NB) {
    __shared__ int pos[256];
    int b = blockIdx.x, tid = threadIdx.x;
    int bstart = H[(size_t)b * NCH];
    int bend = (b + 1 < NB) ? H[(size_t)(b + 1) * NCH] : E;
    int n = (b << BSH) + tid;
    int startv = 0;
    if (n < N) {
        startv = bbase[b] + lexcl[n];            // multiple of 8
        rowptr[n] = startv;
    }
    pos[tid] = startv;
    __syncthreads();
    for (int e = bstart + tid; e < bend; e += 256) {
        int p = ep[e];
        int q = atomicAdd(&pos[p >> 20], 1);
        csr_src[q] = p & 0xFFFFF;
    }
    __syncthreads();
    if (n < N) {
        int d = degi[n], d8 = (d + 7) & ~7;
        for (int z = startv + d; z < startv + d8; ++z)
            csr_src[z] = N;                      // pad -> zero row
    }
}

// ---- MFMA GEMM layer 1: t1h(fp16)[N][64] = (x @ W1) * dinv ----
__global__ __launch_bounds__(256) void k_mgemm1(const float* __restrict__ x,
        const float* __restrict__ W1, const float* __restrict__ dinv,
        _Float16* __restrict__ t1h, int N) {
    __shared__ _Float16 sA[64 * 128];   // 16 KB, row 256 B, XOR-swizzled
    __shared__ _Float16 sB[64 * 128];   // 16 KB, sB[n][k] = W1[k][n], swizzled
    int tid = threadIdx.x;
    int row0 = blockIdx.x * 64;
    if (blockIdx.x == 0 && tid < 8)      // zero row N (gather pad target)
        ((f32x4*)(t1h + (size_t)N * H1))[tid] = (f32x4){0.f, 0.f, 0.f, 0.f};
#pragma unroll
    for (int i = 0; i < 8; ++i) {
        int idx4 = tid + 256 * i;        // 0..2047 float4 slots
        int r = idx4 >> 5, c4 = idx4 & 31;
        int row = row0 + r;
        float4 v = make_float4(0.f, 0.f, 0.f, 0.f);
        if (row < N) v = *(const float4*)&x[(size_t)row * DIN + c4 * 4];
        f16x4 h;
        h[0] = (_Float16)v.x; h[1] = (_Float16)v.y;
        h[2] = (_Float16)v.z; h[3] = (_Float16)v.w;
        int byte = (c4 * 8) ^ ((r & 7) << 4);
        *(f16x4*)((char*)sA + r * 256 + byte) = h;
    }
    {
        int n = tid & 63, kq = tid >> 6;  // kq 0..3, 32 k each
        _Float16 tmp[32];
#pragma unroll
        for (int kk = 0; kk < 32; ++kk)
            tmp[kk] = (_Float16)W1[(size_t)(kq * 32 + kk) * H1 + n];
#pragma unroll
        for (int j = 0; j < 4; ++j) {
            int byte = ((kq * 32 + j * 8) * 2) ^ ((n & 7) << 4);
            *(f16x8*)((char*)sB + n * 256 + byte) = *(f16x8*)&tmp[j * 8];
        }
    }
    __syncthreads();
    int lane = tid & 63, w = tid >> 6;
    int lr = lane & 15, kg = lane >> 4;
    f32x4 acc[4] = {};
    int ar = w * 16 + lr;
    const char* pa = (const char*)sA + ar * 256;
    int axor = (ar & 7) << 4;
#pragma unroll
    for (int ks = 0; ks < 4; ++ks) {
        int kb = ks * 64 + kg * 16;
        f16x8 a = *(const f16x8*)(pa + (kb ^ axor));
#pragma unroll
        for (int nt = 0; nt < 4; ++nt) {
            int bn = nt * 16 + lr;
            f16x8 b = *(const f16x8*)((const char*)sB + bn * 256 + (kb ^ ((bn & 7) << 4)));
            acc[nt] = __builtin_amdgcn_mfma_f32_16x16x32_f16(a, b, acc[nt], 0, 0, 0);
        }
    }
#pragma unroll
    for (int rg = 0; rg < 4; ++rg) {
        int R = row0 + w * 16 + kg * 4 + rg;
        if (R < N) {
            float dv = dinv[R];
#pragma unroll
            for (int nt = 0; nt < 4; ++nt)
                t1h[(size_t)R * H1 + nt * 16 + lr] = (_Float16)(acc[nt][rg] * dv);
        }
    }
}

// ---- MFMA GEMM layer 2: t2h(fp16)[N][32] = (agg1h @ W2) * dinv ----
__global__ __launch_bounds__(256) void k_mgemm2(const _Float16* __restrict__ aggh,
        const float* __restrict__ W2, const float* __restrict__ dinv,
        _Float16* __restrict__ t2h, int N) {
    __shared__ _Float16 sA[64 * 64];    // 8 KB
    __shared__ _Float16 sB[32 * 64];    // 4 KB
    int tid = threadIdx.x;
    int row0 = blockIdx.x * 64;
    if (blockIdx.x == 0 && tid < 4)      // zero row N (gather pad target)
        ((f32x4*)(t2h + (size_t)N * H2))[tid] = (f32x4){0.f, 0.f, 0.f, 0.f};
#pragma unroll
    for (int i = 0; i < 2; ++i) {
        int idx8 = tid + 256 * i;        // 0..511 f16x8 chunks
        int r = idx8 >> 3, c8 = idx8 & 7;
        int row = row0 + r;
        f16x8 h = {};
        if (row < N) h = *(const f16x8*)&aggh[(size_t)row * H1 + c8 * 8];
        int byte = (c8 * 16) ^ ((r & 7) << 4);
        *(f16x8*)((char*)sA + r * 128 + byte) = h;
    }
    {
        int n = tid & 31, kq = tid >> 5;  // kq 0..7, 8 k each
        _Float16 tmp[8];
#pragma unroll
        for (int kk = 0; kk < 8; ++kk)
            tmp[kk] = (_Float16)W2[(size_t)(kq * 8 + kk) * H2 + n];
        int byte = (kq * 16) ^ ((n & 7) << 4);
        *(f16x8*)((char*)sB + n * 128 + byte) = *(f16x8*)&tmp[0];
    }
    __syncthreads();
    int lane = tid & 63, w = tid >> 6;
    int lr = lane & 15, kg = lane >> 4;
    f32x4 acc[2] = {};
    int ar = w * 16 + lr;
    const char* pa = (const char*)sA + ar * 128;
    int axor = (ar & 7) << 4;
#pragma unroll
    for (int ks = 0; ks < 2; ++ks) {
        int kb = ks * 64 + kg * 16;
        f16x8 a = *(const f16x8*)(pa + (kb ^ axor));
#pragma unroll
        for (int nt = 0; nt < 2; ++nt) {
            int bn = nt * 16 + lr;
            f16x8 b = *(const f16x8*)((const char*)sB + bn * 128 + (kb ^ ((bn & 7) << 4)));
            acc[nt] = __builtin_amdgcn_mfma_f32_16x16x32_f16(a, b, acc[nt], 0, 0, 0);
        }
    }
#pragma unroll
    for (int rg = 0; rg < 4; ++rg) {
        int R = row0 + w * 16 + kg * 4 + rg;
        if (R < N) {
            float dv = dinv[R];
#pragma unroll
            for (int nt = 0; nt < 2; ++nt)
                t2h[(size_t)R * H2 + nt * 16 + lr] = (_Float16)(acc[nt][rg] * dv);
        }
    }
}

// ---- pull aggregation: 1<<LOGL lanes/node, 16B gathers, no masks ----
// CSR is 8-aligned per node; pad entries index the zero row N -> add 0.
// Indices loaded as 2x int4 per 8-edge batch.
template <int LOGL, bool FUSE>
__global__ __launch_bounds__(256) void k_aggq(const int* __restrict__ rowptr,
        const int* __restrict__ degi, const int* __restrict__ csr_src,
        const float* __restrict__ dinv, const _Float16* __restrict__ tp,
        void* __restrict__ outv, int N) {
    const int L = 1 << LOGL;                 // lanes per node
    const int F = L * 8;                     // feats per row
    int local = threadIdx.x >> LOGL;
    int j = threadIdx.x & (L - 1);           // 16B slice index
    int n = blockIdx.x * (256 >> LOGL) + local;
    if (n >= N) return;
    int start = rowptr[n];                   // multiple of 8
    int deg = degi[n];
    f16x8 sv = *(const f16x8*)&tp[(size_t)n * F + j * 8];
    float acc[8];
#pragma unroll
    for (int t = 0; t < 8; ++t) acc[t] = (float)sv[t];
    for (int k = 0; k < deg; k += 8) {
        int4 ra = *(const int4*)&csr_src[start + k];
        int4 rb = *(const int4*)&csr_src[start + k + 4];
        int idx[8] = {ra.x, ra.y, ra.z, ra.w, rb.x, rb.y, rb.z, rb.w};
        f16x8 g[8];
#pragma unroll
        for (int u = 0; u < 8; ++u)
            g[u] = *(const f16x8*)&tp[(size_t)idx[u] * F + j * 8];
#pragma unroll
        for (int u = 0; u < 8; ++u)
#pragma unroll
            for (int t = 0; t < 8; ++t)
                acc[t] += (float)g[u][t];
    }
    float dv = dinv[n];
    if (FUSE) {                              // fp16(relu(acc*dinv)) -> 16B store
        f16x8 o;
#pragma unroll
        for (int t = 0; t < 8; ++t) o[t] = (_Float16)fmaxf(acc[t] * dv, 0.f);
        *(f16x8*)((_Float16*)outv + (size_t)n * F + j * 8) = o;
    } else {                                 // fp32 -> 2x float4 store
        float* op = (float*)outv + (size_t)n * F + j * 8;
        f32x4 o0 = {acc[0] * dv, acc[1] * dv, acc[2] * dv, acc[3] * dv};
        f32x4 o1 = {acc[4] * dv, acc[5] * dv, acc[6] * dv, acc[7] * dv};
        *(f32x4*)op = o0;
        *(f32x4*)(op + 4) = o1;
    }
}

extern "C" void kernel_launch(void* const* d_in, const int* in_sizes, int n_in,
                              void* d_out, int out_size, void* d_ws, size_t ws_size,
                              hipStream_t stream) {
    const float* x  = (const float*)d_in[0];
    const int*   ei = (const int*)d_in[1];
    const float* W1 = (const float*)d_in[2];
    const float* W2 = (const float*)d_in[3];

    const int N = in_sizes[0] / DIN;   // 100000 (< 2^20, required by ep packing)
    const int E = in_sizes[1] / 2;     // 1600000
    const int* src = ei;
    const int* dst = ei + E;

    const int NB    = (N + (1 << BSH) - 1) >> BSH;   // 391 buckets
    const int NBNCH = NB * NCH;                       // 200192
    const int chunk = (E + NCH - 1) / NCH;            // 3125

    // workspace layout (4-byte elems unless noted)
    float*    dinv    = (float*)d_ws;                     // N
    int*      degi    = (int*)(dinv + N);                 // N
    int*      rowptr  = degi + N;                         // N
    int*      lexcl   = rowptr + N;                       // N
    int*      H       = lexcl + N;                        // NB*NCH
    int*      partial = H + NBNCH;                        // 256
    int*      btot    = partial + 256;                    // 512
    int*      csr_src = btot + 512;                       // E + 8N (aligned slots)
    _Float16* t1h     = (_Float16*)(csr_src + E + 8 * N); // (N+1)*64 halves
    _Float16* agg1h   = t1h + (size_t)(N + 1) * H1;       // N*64 halves
    _Float16* t2h     = t1h;                              // (N+1)*32, reuse
    float*    out     = (float*)d_out;                    // N*32 fp32
    int*      ep      = (int*)t1h;                        // E packed ints, consumed
                                                          // by k_csrA/B pre-gemm1

    // --- counting-sort CSR build (8-aligned rows, no global atomics) ---
    k_hist<<<NCH, 256, 0, stream>>>(dst, H, E, NB, chunk);
    k_scan1<<<(NBNCH + 1023) / 1024, 256, 0, stream>>>(H, H, partial, NBNCH);
    k_scan2<<<1, 256, 0, stream>>>(partial, (NBNCH + 1023) / 1024);
    k_scan3b<<<(NBNCH + 255) / 256, 256, 0, stream>>>(H, partial, NBNCH);
    k_bsort<<<NCH, 256, 0, stream>>>(src, dst, H, ep, E, NB, chunk);
    k_csrA<<<NB, 256, 0, stream>>>(ep, H, degi, dinv, lexcl, btot, E, N, NB);
    k_scanC<<<1, 256, 0, stream>>>(btot, NB);
    k_csrB<<<NB, 256, 0, stream>>>(ep, H, degi, btot, lexcl, rowptr, csr_src, E, N, NB);

    const int ntile = (N + 63) / 64;                 // 1563

    // --- layer 1 ---
    k_mgemm1<<<ntile, 256, 0, stream>>>(x, W1, dinv, t1h, N);
    k_aggq<3, true><<<(N + 31) / 32, 256, 0, stream>>>(rowptr, degi, csr_src, dinv,
                                                       t1h, agg1h, N);

    // --- layer 2 ---
    k_mgemm2<<<ntile, 256, 0, stream>>>(agg1h, W2, dinv, t2h, N);
    k_aggq<2, false><<<(N + 63) / 64, 256, 0, stream>>>(rowptr, degi, csr_src, dinv,
                                                        t2h, out, N);
}